// Round 9
// baseline (1150.604 us; speedup 1.0000x reference)
//
#include <hip/hip_runtime.h>
#include <hip/hip_bf16.h>
#include <stdint.h>

// out[b,t,k,f] = sum_d x[b,t,d] * (qw[k,d,f]-qz[k,d/128,f])*sc[k,d/128,f]
// Stage 1: FRAGMENT-LINEAR bf16 panels in d_ws (R8 layout): panel 16KB = 16
//   fragments of 1KB; fragment = 64 lanes x 16B mfma_32x32x16 operand slices.
//   LDS fragment read = linear base + lane*16 (0 conflicts, 0 addr VALU).
// Stage 2: 256x256x64 8-phase double-buffered GEMM, mfma_f32_32x32x16_bf16.
// R9: fragment reads prefetched ONE PHASE EARLY into double register sets;
//   NO hand-written lgkm waits — compiler emits counted lgkmcnt(N) so the
//   prefetch stays outstanding under the MFMA cluster (LDS drain hidden).
//   R5's failure isolated: its asm lgkmcnt(0) waited on the prefetch too.
//   Barrier/STAGE/vmcnt ledger identical to R8 (verified disjoint with
//   reads in flight across barriers).

typedef __attribute__((ext_vector_type(8))) short bf16x8;
typedef __attribute__((ext_vector_type(16))) float f32x16;
typedef __attribute__((ext_vector_type(4))) float f32x4;

static constexpr int Dd = 4096, Ff = 8192;
static constexpr int M = 8192, NTOT = 16384;
static constexpr int NKT = Dd / 64;       // 64 K-tiles
static constexpr int NMB = M / 256;       // 32
static constexpr int NNB = NTOT / 256;    // 64

__device__ __forceinline__ short f2bf(float f) {
    __hip_bfloat16 h = __float2bfloat16(f);
    return *reinterpret_cast<short*>(&h);
}

// fragment-linear byte offset within a 16KB panel: row r (0..127), 8-elem
// k-group cb (0..7; k = cb*8..cb*8+8)
__device__ __forceinline__ int frag_off(int r, int cb) {
    const int rb = r >> 5, ks = cb >> 1, kh = cb & 1;
    return ((rb * 4 + ks) << 10) + (((r & 31) + 32 * kh) << 4);
}

// ---------------- Stage 1a: x fp32 -> fragment-linear bf16 A-panels ----------------
__global__ __launch_bounds__(256) void xcvt(const float* __restrict__ x,
                                            char* __restrict__ Xw) {
    const int bid = blockIdx.x;             // h*64 + kt, h in [0,64)
    const int h = bid >> 6, kt = bid & 63;
    const int t = threadIdx.x;
    const int r = t >> 1, seg = t & 1;
    const float* src = x + ((size_t)(h * 128 + r)) * Dd + kt * 64 + seg * 32;
    char* panel = Xw + ((size_t)bid << 14);
    #pragma unroll
    for (int jj = 0; jj < 4; ++jj) {
        float4 v0 = *reinterpret_cast<const float4*>(src + jj * 8);
        float4 v1 = *reinterpret_cast<const float4*>(src + jj * 8 + 4);
        union { short s[8]; bf16x8 v; } u;
        u.s[0] = f2bf(v0.x); u.s[1] = f2bf(v0.y); u.s[2] = f2bf(v0.z); u.s[3] = f2bf(v0.w);
        u.s[4] = f2bf(v1.x); u.s[5] = f2bf(v1.y); u.s[6] = f2bf(v1.z); u.s[7] = f2bf(v1.w);
        const int cb = seg * 4 + jj;        // k = cb*8 .. +8
        *reinterpret_cast<bf16x8*>(panel + frag_off(r, cb)) = u.v;
    }
}

// ---------------- Stage 1b: dequant int4 -> fragment-linear bf16 B^T panels ----------------
__global__ __launch_bounds__(256) void wdq(const int* __restrict__ qw,
                                           const int* __restrict__ qz,
                                           const float* __restrict__ sc,
                                           char* __restrict__ Ww) {
    const int bid = blockIdx.x;             // fh*64 + kt, fh in [0,128)
    const int fh = bid >> 6, kt = bid & 63;
    const int t = threadIdx.x;
    const int r = t & 127, dh = t >> 7;
    const int n = fh * 128 + r;
    const int k = n >> 13, f = n & 8191;
    const int g = kt >> 1;                  // 64-col tile within one 128-group
    const int   zv = qz[((size_t)k * 32 + g) * Ff + f];
    const float sv = sc[((size_t)k * 32 + g) * Ff + f];
    const int* qp = qw + ((size_t)(k * Dd + kt * 64 + dh * 32)) * Ff + f;
    char* panel = Ww + ((size_t)bid << 14);
    #pragma unroll
    for (int jj = 0; jj < 4; ++jj) {
        union { short s[8]; bf16x8 v; } u;
        #pragma unroll
        for (int e = 0; e < 8; ++e) {
            int q = qp[(size_t)(jj * 8 + e) * Ff];
            u.s[e] = f2bf((float)(q - zv) * sv);
        }
        const int cb = dh * 4 + jj;         // k = cb*8 .. +8
        *reinterpret_cast<bf16x8*>(panel + frag_off(r, cb)) = u.v;
    }
}

// ---------------- Stage 2: 256x256 8-phase GEMM (32x32x16, prefetched frags) ----------------
#define APAN(HALF, KT) (Xw + (((size_t)(bm2 + (HALF)) * 64 + (KT)) << 14))
#define BPAN(HALF, KT) (Ww + (((size_t)(bn2 + (HALF)) * 64 + (KT)) << 14))

#define STAGE(GP, LP) do {                                                         \
    const char* _g = (GP) + woff16;                                                \
    char* _l = (LP) + woffu;                                                       \
    __builtin_amdgcn_global_load_lds(                                              \
        (const __attribute__((address_space(1))) void*)(_g),                       \
        (__attribute__((address_space(3))) void*)(_l), 16, 0, 0);                  \
    __builtin_amdgcn_global_load_lds(                                              \
        (const __attribute__((address_space(1))) void*)(_g + 8192),                \
        (__attribute__((address_space(3))) void*)(_l + 8192), 16, 0, 0);           \
} while (0)

#define SB0() __builtin_amdgcn_sched_barrier(0)
#define BARW() do { SB0(); __builtin_amdgcn_s_barrier(); SB0(); } while (0)

// 4 A-fragment reads (mf x kq) for m-half H, k-pair KS2, into DST[mf*2+kq]
#define RDA4(DST, LA, H, KS2) do {                                                 \
    _Pragma("unroll")                                                              \
    for (int mf = 0; mf < 2; ++mf)                                                 \
        _Pragma("unroll")                                                          \
        for (int kq = 0; kq < 2; ++kq)                                             \
            DST[mf * 2 + kq] = *reinterpret_cast<const bf16x8*>(                   \
                (LA) + abase + (((((H) * 2 + mf) * 4) + (KS2) + kq) << 10) + lane16); \
} while (0)

// 4 B-fragment reads (nf x kq) for k-pair KS2, into DST[nf*2+kq]
#define RDB4(DST, LB, KS2) do {                                                    \
    _Pragma("unroll")                                                              \
    for (int nf = 0; nf < 2; ++nf)                                                 \
        _Pragma("unroll")                                                          \
        for (int kq = 0; kq < 2; ++kq)                                             \
            DST[nf * 2 + kq] = *reinterpret_cast<const bf16x8*>(                   \
                (LB) + bbase + ((nf * 4 + (KS2) + kq) << 10) + lane16);            \
} while (0)

// 8 x mfma_32x32x16 cluster for m-half H (acc indexed by H,mf,nf only)
#define MM(H, AF, BB) do {                                                         \
    __builtin_amdgcn_s_setprio(1);                                                 \
    _Pragma("unroll")                                                              \
    for (int kq = 0; kq < 2; ++kq)                                                 \
        _Pragma("unroll")                                                          \
        for (int mf = 0; mf < 2; ++mf)                                             \
            _Pragma("unroll")                                                      \
            for (int nf = 0; nf < 2; ++nf)                                         \
                acc[((H) * 2 + mf) * 2 + nf] = __builtin_amdgcn_mfma_f32_32x32x16_bf16( \
                    AF[mf * 2 + kq], BB[nf * 2 + kq],                              \
                    acc[((H) * 2 + mf) * 2 + nf], 0, 0, 0);                        \
    __builtin_amdgcn_s_setprio(0);                                                 \
} while (0)

__global__ __launch_bounds__(512, 2) void gemm256(const char* __restrict__ Xw,
                                                  const char* __restrict__ Ww,
                                                  float* __restrict__ out) {
    __shared__ char lds[131072];
    char* lA0 = lds;
    char* lB0 = lds + 32768;
    char* lA1 = lds + 65536;
    char* lB1 = lds + 98304;

    const int t = threadIdx.x;
    const int wave = t >> 6, lane = t & 63;
    const int wm = wave >> 2, wn = wave & 3;      // 2 x 4 waves, 128x64 per wave
    const int l31 = lane & 31;
    const int lane16 = lane << 4;

    // bijective XCD swizzle (2048 % 8 == 0); n-chunked for B-slab L2 residency
    const int xcd = blockIdx.x & 7;
    const int c   = blockIdx.x >> 3;              // 0..255
    const int bn  = xcd * 8 + (c >> 5);           // 0..63
    const int bm  = c & 31;                       // 0..31
    const int bm2 = bm * 2, bn2 = bn * 2;

    const int woff16 = wave * 1024 + lane16;      // per-lane global offset
    const int woffu  = wave * 1024;               // wave-uniform LDS offset
    const int abase = wm * 16384;                 // wave's A panel (128 rows)
    const int bbase = (wn >> 1) * 16384 + (wn & 1) * 8192;  // wave's 64-row B slab

    bf16x8 afX[4], afY[4], bbX[4], bbY[4];
    f32x16 acc[8] = {};   // [mf 0..3][nf 0..1]

    // prologue: tile0 (4 halves) + tile1.B0; wait tile0; sync
    STAGE(APAN(0, 0), lA0);
    STAGE(APAN(1, 0), lA0 + 16384);
    STAGE(BPAN(0, 0), lB0);
    STAGE(BPAN(1, 0), lB0 + 16384);
    STAGE(BPAN(0, 1), lB1);
    asm volatile("s_waitcnt vmcnt(2)" ::: "memory");
    BARW();

    for (int i = 0; i < 32; ++i) {
        const int kt0 = 2 * i;
        const bool nl = (i < 31);
        // ---------- K-tile kt0 from buf0 ----------
        // P1: own frags (H0,ks01) + prefetch P2's A(H1,ks01)
        STAGE(BPAN(1, kt0 + 1), lB1 + 16384);
        BARW();
        RDB4(bbX, lB0, 0); RDA4(afX, lA0, 0, 0);
        RDA4(afY, lA0, 1, 0);
        SB0();
        MM(0, afX, bbX);
        BARW();
        // P2: prefetch P3's B(ks23)+A(H0,ks23)
        STAGE(APAN(0, kt0 + 1), lA1);
        BARW();
        RDB4(bbY, lB0, 2); RDA4(afX, lA0, 0, 2);
        SB0();
        MM(1, afY, bbX);
        BARW();
        // P3: prefetch P4's A(H1,ks23)
        STAGE(APAN(1, kt0 + 1), lA1 + 16384);
        BARW();
        RDA4(afY, lA0, 1, 2);
        SB0();
        MM(0, afX, bbY);
        BARW();
        // P4: no prefetch (next reads need buf1 certification)
        if (nl) STAGE(BPAN(0, kt0 + 2), lB0);
        BARW();
        SB0();
        MM(1, afY, bbY);
        if (nl) asm volatile("s_waitcnt vmcnt(2)" ::: "memory");
        else    asm volatile("s_waitcnt vmcnt(0)" ::: "memory");
        BARW();
        // ---------- K-tile kt0+1 from buf1 ----------
        // P5
        if (nl) STAGE(BPAN(1, kt0 + 2), lB0 + 16384);
        BARW();
        RDB4(bbX, lB1, 0); RDA4(afX, lA1, 0, 0);
        RDA4(afY, lA1, 1, 0);
        SB0();
        MM(0, afX, bbX);
        BARW();
        // P6
        if (nl) STAGE(APAN(0, kt0 + 2), lA0);
        BARW();
        RDB4(bbY, lB1, 2); RDA4(afX, lA1, 0, 2);
        SB0();
        MM(1, afY, bbX);
        BARW();
        // P7
        if (nl) STAGE(APAN(1, kt0 + 2), lA0 + 16384);
        BARW();
        RDA4(afY, lA1, 1, 2);
        SB0();
        MM(0, afX, bbY);
        BARW();
        // P8
        if (nl) STAGE(BPAN(0, kt0 + 3), lB1);
        BARW();
        SB0();
        MM(1, afY, bbY);
        if (nl) asm volatile("s_waitcnt vmcnt(2)" ::: "memory");
        else    asm volatile("s_waitcnt vmcnt(0)" ::: "memory");
        BARW();
    }

    // epilogue: 32x32 C/D layout: col=lane&31, row=(reg&3)+8*(reg>>2)+4*(lane>>5)
    const int rbase = bm * 256 + wm * 128 + (lane >> 5) * 4;
    const int cbase = bn * 256 + wn * 64 + l31;
    #pragma unroll
    for (int mf = 0; mf < 4; ++mf)
        #pragma unroll
        for (int nf = 0; nf < 2; ++nf)
            #pragma unroll
            for (int reg = 0; reg < 16; ++reg) {
                const int row = rbase + mf * 32 + (reg & 3) + 8 * (reg >> 2);
                out[(size_t)row * NTOT + cbase + nf * 32] = acc[mf * 2 + nf][reg];
            }
}

// ---------------- Fallback (ws too small): round-1 fused kernel ----------------
#define LDP 72
__global__ __launch_bounds__(256) void int4_gemm(
    const float* __restrict__ x, const int* __restrict__ qw,
    const int* __restrict__ qz, const float* __restrict__ sc,
    float* __restrict__ out)
{
    __shared__ short As[128][LDP];
    __shared__ short Bs[128][LDP];
    const int t = threadIdx.x;
    int gid = (blockIdx.x & 7) * 1024 + (blockIdx.x >> 3);
    const int bm = gid & 63;
    const int bnq = gid >> 6;
    const int kse = bnq >> 6;
    const int f0  = (bnq & 63) * 128;
    const int m0  = bm * 128;
    const int wave = t >> 6, lane = t & 63;
    const int wm = wave >> 1, wn = wave & 1;
    const int l15 = lane & 15, lhi = lane >> 4;
    const int am = t >> 4, ad = (t & 15) * 4;
    const int bf = t & 127, bd = (t >> 7) * 4;
    const int*   qwk = qw + (size_t)kse * Dd * Ff;
    const int*   qzk = qz + (size_t)kse * 32 * Ff;
    const float* sck = sc + (size_t)kse * 32 * Ff;
    f32x4 acc[4][4] = {};
    for (int d0 = 0; d0 < Dd; d0 += 64) {
        __syncthreads();
        #pragma unroll
        for (int p = 0; p < 8; ++p) {
            int m = p * 16 + am;
            const float4 v = *reinterpret_cast<const float4*>(
                &x[(size_t)(m0 + m) * Dd + d0 + ad]);
            short4 wv;
            wv.x = f2bf(v.x); wv.y = f2bf(v.y); wv.z = f2bf(v.z); wv.w = f2bf(v.w);
            *reinterpret_cast<short4*>(&As[m][ad]) = wv;
        }
        {
            const int g = d0 >> 7;
            const int   zv = qzk[g * Ff + f0 + bf];
            const float sv = sck[g * Ff + f0 + bf];
            #pragma unroll
            for (int p = 0; p < 8; ++p) {
                int dl = p * 8 + bd;
                const int* qp = qwk + (size_t)(d0 + dl) * Ff + f0 + bf;
                short4 wv;
                wv.x = f2bf((float)(qp[0]      - zv) * sv);
                wv.y = f2bf((float)(qp[Ff]     - zv) * sv);
                wv.z = f2bf((float)(qp[2 * Ff] - zv) * sv);
                wv.w = f2bf((float)(qp[3 * Ff] - zv) * sv);
                *reinterpret_cast<short4*>(&Bs[bf][dl]) = wv;
            }
        }
        __syncthreads();
        #pragma unroll
        for (int kk = 0; kk < 64; kk += 32) {
            bf16x8 a2[4], b2[4];
            #pragma unroll
            for (int i = 0; i < 4; ++i)
                a2[i] = *reinterpret_cast<const bf16x8*>(&As[wm * 64 + i * 16 + l15][kk + lhi * 8]);
            #pragma unroll
            for (int i = 0; i < 4; ++i)
                b2[i] = *reinterpret_cast<const bf16x8*>(&Bs[wn * 64 + i * 16 + l15][kk + lhi * 8]);
            #pragma unroll
            for (int mi = 0; mi < 4; ++mi)
                #pragma unroll
                for (int ni = 0; ni < 4; ++ni)
                    acc[mi][ni] = __builtin_amdgcn_mfma_f32_16x16x32_bf16(
                        a2[mi], b2[ni], acc[mi][ni], 0, 0, 0);
        }
    }
    const int crow0 = m0 + wm * 64 + lhi * 4;
    const int ccol0 = bnq * 128 + wn * 64 + l15;
    #pragma unroll
    for (int mi = 0; mi < 4; ++mi)
        #pragma unroll
        for (int ni = 0; ni < 4; ++ni)
            #pragma unroll
            for (int r = 0; r < 4; ++r)
                out[(size_t)(crow0 + mi * 16 + r) * NTOT + ccol0 + ni * 16] =
                    acc[mi][ni][r];
}

extern "C" void kernel_launch(void* const* d_in, const int* in_sizes, int n_in,
                              void* d_out, int out_size, void* d_ws, size_t ws_size,
                              hipStream_t stream) {
    const float* x  = (const float*)d_in[0];
    const int*   qw = (const int*)d_in[1];
    const int*   qz = (const int*)d_in[2];
    const float* sc = (const float*)d_in[3];
    float*       out = (float*)d_out;

    const size_t xw_bytes = (size_t)(M / 128) * NKT * 16384;      // 64 MiB
    const size_t ww_bytes = (size_t)(NTOT / 128) * NKT * 16384;   // 128 MiB

    if (ws_size >= xw_bytes + ww_bytes) {
        char* Xw = (char*)d_ws;
        char* Ww = Xw + xw_bytes;
        hipLaunchKernelGGL(xcvt, dim3((M / 128) * NKT), dim3(256), 0, stream, x, Xw);
        hipLaunchKernelGGL(wdq, dim3((NTOT / 128) * NKT), dim3(256), 0, stream,
                           qw, qz, sc, Ww);
        hipLaunchKernelGGL(gemm256, dim3(NMB * NNB), dim3(512), 0, stream,
                           Xw, Ww, out);
    } else {
        hipLaunchKernelGGL(int4_gemm, dim3(8192), dim3(256), 0, stream,
                           x, qw, qz, sc, out);
    }
}